// Round 1
// baseline (173.163 us; speedup 1.0000x reference)
//
#include <hip/hip_runtime.h>
#include <math.h>

#define NCLS 80
#define EPSF 1e-7f

struct Tgt { int key; float tx, ty, tw, th; int label; int pad0, pad1; };

__constant__ float c_anch[3][3][2] = {
    {{80.f,104.f},{128.f,240.f},{264.f,184.f}},
    {{480.f,976.f},{992.f,720.f},{944.f,1904.f}},
    {{3712.f,2880.f},{4992.f,6336.f},{11936.f,10432.f}}
};
__constant__ float c_stride[3] = {8.f, 16.f, 32.f};
__constant__ float c_bal[3]    = {4.f, 1.f, 0.4f};
__constant__ int   c_H[3]      = {80, 40, 20};

// ---------------------------------------------------------------------------
// Kernel 1: per-(scale,batch) target build. 48 active threads, 1 block.
// ---------------------------------------------------------------------------
__global__ void build_targets(const float* __restrict__ boxes,
                              const int*   __restrict__ labels,
                              Tgt*  __restrict__ tgt,
                              float* __restrict__ acc,
                              int*   __restrict__ npos)
{
    int tid = threadIdx.x;
    if (tid < 12) acc[tid] = 0.f;   // 9 used accumulators (+pad)
    if (tid < 3)  npos[tid] = 0;
    __syncthreads();
    if (tid >= 48) return;

    int s = tid / 16;
    int b = tid % 16;
    const float stride = c_stride[s];
    const int H = c_H[s];
    const int W = H;

    int keys[32];
    for (int n = 0; n < 32; ++n) {
        const float* bx = boxes + ((size_t)b * 32 + n) * 4;
        float x1 = bx[0], y1 = bx[1], x2 = bx[2], y2 = bx[3];
        float cx = (x1 + x2) * 0.5f, cy = (y1 + y2) * 0.5f;
        float w  = x2 - x1,          h  = y2 - y1;
        float xg = cx / stride, yg = cy / stride;
        int gi = min(max((int)yg, 0), H - 1);   // row from y
        int gj = min(max((int)xg, 0), W - 1);   // col from x
        // best anchor = argmin shape metric (first wins on ties)
        int best = 0; float bm = 1e30f;
        for (int k = 0; k < 3; ++k) {
            float aw = c_anch[s][k][0], ah = c_anch[s][k][1];
            float r0 = w / aw, r1 = h / ah;
            float m = fmaxf(r0, 1.f / r0) * fmaxf(r1, 1.f / r1);
            if (m < bm) { bm = m; best = k; }
        }
        float aw = c_anch[s][best][0], ah = c_anch[s][best][1];
        Tgt t;
        t.key = (best << 20) | (gi << 10) | gj;
        t.tx  = xg - (float)gj;
        t.ty  = yg - (float)gi;
        t.tw  = logf(w / (aw + 1e-16f));
        t.th  = logf(h / (ah + 1e-16f));
        t.label = labels[b * 32 + n];
        t.pad0 = 0; t.pad1 = 0;
        tgt[((size_t)s * 16 + b) * 32 + n] = t;
        keys[n] = t.key;
    }
    // npos = number of distinct target cells for this (s,b)
    int cnt = 0;
    for (int n = 0; n < 32; ++n) {
        bool uniq = true;
        for (int m = n + 1; m < 32; ++m)
            if (keys[m] == keys[n]) uniq = false;
        cnt += uniq;
    }
    atomicAdd(&npos[s], cnt);
}

// ---------------------------------------------------------------------------
// Kernel 2: per-cell loss, all 3 scales in one launch.
//   blocks: s0 -> 1200 (cpb=25), s1 -> 336 (cpb=7), s2 -> 96 (cpb=2)
// ---------------------------------------------------------------------------
__global__ __launch_bounds__(256) void scale_loss(
        const float* __restrict__ p0, const float* __restrict__ p1,
        const float* __restrict__ p2,
        const Tgt* __restrict__ tgt, float* __restrict__ acc)
{
    int bid = blockIdx.x;
    int s, rem, cpb;
    if (bid < 1200)      { s = 0; rem = bid;        cpb = 25; }
    else if (bid < 1536) { s = 1; rem = bid - 1200; cpb = 7;  }
    else                 { s = 2; rem = bid - 1536; cpb = 2;  }
    int b     = rem / (3 * cpb);
    int a     = (rem / cpb) % 3;
    int chunk = rem % cpb;
    const int H = c_H[s], W = H, HW = H * W;
    int hw = chunk * 256 + threadIdx.x;
    const float* pred = (s == 0) ? p0 : ((s == 1) ? p1 : p2);

    __shared__ Tgt sT[32];
    if (threadIdx.x < 32) sT[threadIdx.x] = tgt[((size_t)s * 16 + b) * 32 + threadIdx.x];
    __syncthreads();

    float boxc = 0.f, objc = 0.f, clsc = 0.f;
    if (hw < HW) {
        int h = hw / W, w = hw % W;
        int key = (a << 20) | (h << 10) | w;
        int src = -1;                      // last n wins (scatter-set semantics)
        #pragma unroll
        for (int n = 0; n < 32; ++n)
            if (sT[n].key == key) src = n;

        // objectness BCE at every cell
        float x  = pred[((size_t)b * 255 + a * 85 + 4) * HW + hw];
        float to = (src >= 0) ? 1.f : 0.f;
        float bce = fmaxf(x, 0.f) - x * to + log1pf(expf(-fabsf(x)));
        objc = c_bal[s] * bce * (0.5f + 0.5f * to);

        if (src >= 0) {
            const float stride = c_stride[s];
            const float aw = c_anch[s][a][0], ah = c_anch[s][a][1];
            const float* pb = pred + ((size_t)b * 255 + a * 85) * HW + hw;
            float px = pb[0], py = pb[(size_t)HW], pw = pb[2 * (size_t)HW], ph = pb[3 * (size_t)HW];
            float sx = 1.f / (1.f + expf(-px));
            float sy = 1.f / (1.f + expf(-py));
            float b1x = (sx + (float)w) * stride, b1y = (sy + (float)h) * stride;
            float b1w = expf(pw) * aw,            b1h = expf(ph) * ah;

            Tgt t = sT[src];
            float b2x = ((float)w + t.tx) * stride, b2y = ((float)h + t.ty) * stride;
            float b2w = expf(t.tw) * aw,            b2h = expf(t.th) * ah;

            // CIoU
            float b1x1 = b1x - b1w * 0.5f, b1x2 = b1x + b1w * 0.5f;
            float b1y1 = b1y - b1h * 0.5f, b1y2 = b1y + b1h * 0.5f;
            float b2x1 = b2x - b2w * 0.5f, b2x2 = b2x + b2w * 0.5f;
            float b2y1 = b2y - b2h * 0.5f, b2y2 = b2y + b2h * 0.5f;
            float iw = fmaxf(fminf(b1x2, b2x2) - fmaxf(b1x1, b2x1), 0.f);
            float ih = fmaxf(fminf(b1y2, b2y2) - fmaxf(b1y1, b2y1), 0.f);
            float inter = iw * ih;
            float uni = b1w * b1h + b2w * b2h - inter + EPSF;
            float iou = inter / uni;
            float cwv = fmaxf(b1x2, b2x2) - fminf(b1x1, b2x1);
            float chv = fmaxf(b1y2, b2y2) - fminf(b1y1, b2y1);
            float c2 = cwv * cwv + chv * chv + EPSF;
            float dx = b2x1 + b2x2 - b1x1 - b1x2;
            float dy = b2y1 + b2y2 - b1y1 - b1y2;
            float rho2 = (dx * dx + dy * dy) * 0.25f;
            float dat = atanf(b2w / (b2h + EPSF)) - atanf(b1w / (b1h + EPSF));
            float v = (4.f / (float)(M_PI * M_PI)) * dat * dat;
            float alpha = v / (v - iou + 1.f + EPSF);
            float ciou = iou - (rho2 / c2 + v * alpha);
            boxc = 1.f - ciou;

            // class BCE (only positives contribute)
            const float* pc = pred + ((size_t)b * 255 + a * 85 + 5) * HW + hw;
            int lab = t.label;
            for (int c = 0; c < NCLS; ++c) {
                float xc = pc[(size_t)c * HW];
                float tc = (c == lab) ? 1.f : 0.f;
                clsc += fmaxf(xc, 0.f) - xc * tc + log1pf(expf(-fabsf(xc)));
            }
        }
    }

    // block reduce: wave64 shfl + cross-wave LDS
    for (int off = 32; off > 0; off >>= 1) {
        boxc += __shfl_down(boxc, off);
        objc += __shfl_down(objc, off);
        clsc += __shfl_down(clsc, off);
    }
    __shared__ float red[4][3];
    int wave = threadIdx.x >> 6, lane = threadIdx.x & 63;
    if (lane == 0) { red[wave][0] = boxc; red[wave][1] = objc; red[wave][2] = clsc; }
    __syncthreads();
    if (threadIdx.x == 0) {
        float bs = 0.f, os = 0.f, cs = 0.f;
        for (int i = 0; i < 4; ++i) { bs += red[i][0]; os += red[i][1]; cs += red[i][2]; }
        atomicAdd(&acc[s * 3 + 0], bs);
        atomicAdd(&acc[s * 3 + 1], os);
        atomicAdd(&acc[s * 3 + 2], cs);
    }
}

// ---------------------------------------------------------------------------
// Kernel 3: combine
// ---------------------------------------------------------------------------
__global__ void finalize(const float* __restrict__ acc,
                         const int* __restrict__ npos,
                         float* __restrict__ out)
{
    if (threadIdx.x == 0) {
        float tot = 0.f;
        for (int s = 0; s < 3; ++s) {
            float np = fmaxf((float)npos[s], 1.f);
            tot += acc[s * 3 + 0] / np      // LAMBDA_IOU = 1
                 + acc[s * 3 + 1]           // LAMBDA_OBJ = 1 (balance folded in)
                 + 0.5f * acc[s * 3 + 2];   // LAMBDA_CLS = 0.5
        }
        out[0] = tot / 16.f;                // / B
    }
}

extern "C" void kernel_launch(void* const* d_in, const int* in_sizes, int n_in,
                              void* d_out, int out_size, void* d_ws, size_t ws_size,
                              hipStream_t stream)
{
    const float* p0     = (const float*)d_in[0];
    const float* p1     = (const float*)d_in[1];
    const float* p2     = (const float*)d_in[2];
    const float* boxes  = (const float*)d_in[3];
    const int*   labels = (const int*)d_in[4];

    Tgt*   tgt  = (Tgt*)d_ws;                                   // 1536 * 32B = 49152B
    float* acc  = (float*)((char*)d_ws + 49152);                // 12 floats
    int*   npos = (int*)((char*)d_ws + 49152 + 48);             // 3 ints

    build_targets<<<1, 64, 0, stream>>>(boxes, labels, tgt, acc, npos);
    scale_loss<<<1632, 256, 0, stream>>>(p0, p1, p2, tgt, acc);
    finalize<<<1, 64, 0, stream>>>(acc, npos, (float*)d_out);
}

// Round 2
// 56.457 us; speedup vs baseline: 3.0672x; 3.0672x over previous
//
#include <hip/hip_runtime.h>
#include <math.h>

#define EPSF 1e-7f

struct Tgt { int key; float tx, ty, tw, th; int label; int pad0, pad1; };

__constant__ float c_anch[3][3][2] = {
    {{80.f,104.f},{128.f,240.f},{264.f,184.f}},
    {{480.f,976.f},{992.f,720.f},{944.f,1904.f}},
    {{3712.f,2880.f},{4992.f,6336.f},{11936.f,10432.f}}
};
__constant__ float c_stride[3] = {8.f, 16.f, 32.f};
__constant__ float c_bal[3]    = {4.f, 1.f, 0.4f};
__constant__ int   c_HW[3]     = {6400, 1600, 400};
__constant__ int   c_W[3]      = {80, 40, 20};

__device__ __forceinline__ float bce0(float x) {
    // BCE with target 0: max(x,0) + log(1+exp(-|x|))
    return fmaxf(x, 0.f) + __logf(1.f + __expf(-fabsf(x)));
}

// ---------------------------------------------------------------------------
// Kernel 1: per-(scale,batch) target build + winner mask (last-n-wins dedup).
// ---------------------------------------------------------------------------
__global__ void build_targets(const float* __restrict__ boxes,
                              const int*   __restrict__ labels,
                              Tgt*  __restrict__ tgt,
                              unsigned int* __restrict__ winmask,
                              int*   __restrict__ npos)
{
    int tid = threadIdx.x;
    if (tid < 3) npos[tid] = 0;
    __syncthreads();
    if (tid >= 48) return;

    int s = tid / 16;
    int b = tid % 16;
    const float stride = c_stride[s];
    const int W = c_W[s], H = W;

    int keys[32];
    for (int n = 0; n < 32; ++n) {
        const float* bx = boxes + ((size_t)b * 32 + n) * 4;
        float x1 = bx[0], y1 = bx[1], x2 = bx[2], y2 = bx[3];
        float cx = (x1 + x2) * 0.5f, cy = (y1 + y2) * 0.5f;
        float w  = x2 - x1,          h  = y2 - y1;
        float xg = cx / stride, yg = cy / stride;
        int gi = min(max((int)yg, 0), H - 1);   // row from y
        int gj = min(max((int)xg, 0), W - 1);   // col from x
        int best = 0; float bm = 1e30f;
        for (int k = 0; k < 3; ++k) {
            float aw = c_anch[s][k][0], ah = c_anch[s][k][1];
            float r0 = w / aw, r1 = h / ah;
            float m = fmaxf(r0, 1.f / r0) * fmaxf(r1, 1.f / r1);
            if (m < bm) { bm = m; best = k; }
        }
        float aw = c_anch[s][best][0], ah = c_anch[s][best][1];
        Tgt t;
        t.key = (best << 20) | (gi << 10) | gj;
        t.tx  = xg - (float)gj;
        t.ty  = yg - (float)gi;
        t.tw  = logf(w / (aw + 1e-16f));
        t.th  = logf(h / (ah + 1e-16f));
        t.label = labels[b * 32 + n];
        t.pad0 = 0; t.pad1 = 0;
        tgt[((size_t)s * 16 + b) * 32 + n] = t;
        keys[n] = t.key;
    }
    // winner = entry n such that no m>n has the same key (last-wins scatter)
    unsigned int mask = 0u;
    for (int n = 0; n < 32; ++n) {
        bool win = true;
        for (int m = n + 1; m < 32; ++m)
            if (keys[m] == keys[n]) win = false;
        mask |= (win ? 1u : 0u) << n;
    }
    winmask[s * 16 + b] = mask;
    atomicAdd(&npos[s], __popc(mask));
}

// ---------------------------------------------------------------------------
// Kernel 2: dense objectness pass — pure streaming float4 reduce, no matching.
//   Accumulates  0.5 * bal[s] * bce0(x)  over all cells of the 3 obj channels.
//   100800 float4 elements total -> 394 blocks x 256.
// ---------------------------------------------------------------------------
__global__ __launch_bounds__(256) void dense_obj(
        const float* __restrict__ p0, const float* __restrict__ p1,
        const float* __restrict__ p2, float* __restrict__ densePart)
{
    int v = blockIdx.x * 256 + threadIdx.x;
    float sum = 0.f;
    if (v < 100800) {
        int s, run, off, HW;
        const float* pred;
        if (v < 76800)      { s = 0; HW = 6400; run = v / 1600;          off = v - run * 1600;          pred = p0; }
        else if (v < 96000) { s = 1; HW = 1600; int u = v - 76800; run = u / 400; off = u - run * 400;  pred = p1; }
        else                { s = 2; HW = 400;  int u = v - 96000; run = u / 100; off = u - run * 100;  pred = p2; }
        int b = run / 3, a = run - b * 3;
        const float4* ptr = (const float4*)(pred + (size_t)(b * 255 + a * 85 + 4) * HW) + off;
        float4 x = *ptr;
        float w = 0.5f * c_bal[s];
        sum = w * (bce0(x.x) + bce0(x.y) + bce0(x.z) + bce0(x.w));
    }
    for (int o = 32; o > 0; o >>= 1) sum += __shfl_down(sum, o);
    __shared__ float red[4];
    int wv = threadIdx.x >> 6;
    if ((threadIdx.x & 63) == 0) red[wv] = sum;
    __syncthreads();
    if (threadIdx.x == 0)
        densePart[blockIdx.x] = red[0] + red[1] + red[2] + red[3];
}

// ---------------------------------------------------------------------------
// Kernel 3: positive cells — one wave per target, lane-parallel class BCE.
//   1536 targets -> 384 blocks x 256 (4 waves each; 128 blocks per scale).
//   Per block writes {box_sum, obj_corr_sum, cls_sum} partials.
// ---------------------------------------------------------------------------
__global__ __launch_bounds__(256) void pos_loss(
        const float* __restrict__ p0, const float* __restrict__ p1,
        const float* __restrict__ p2,
        const Tgt* __restrict__ tgt, const unsigned int* __restrict__ winmask,
        float* __restrict__ posPart)
{
    int gw   = blockIdx.x * 4 + (threadIdx.x >> 6);   // global wave id, 0..1535
    int lane = threadIdx.x & 63;
    int s = gw >> 9;            // 512 targets per scale
    int b = (gw >> 5) & 15;
    int n = gw & 31;

    float boxc = 0.f, objc = 0.f, clsp = 0.f;
    unsigned int mask = winmask[s * 16 + b];
    if ((mask >> n) & 1u) {
        Tgt t = tgt[((size_t)s * 16 + b) * 32 + n];
        int a  = t.key >> 20;
        int gi = (t.key >> 10) & 1023;
        int gj = t.key & 1023;
        const int HW = c_HW[s], W = c_W[s];
        int hw = gi * W + gj;
        const float* pred = (s == 0) ? p0 : ((s == 1) ? p1 : p2);
        const float* pb = pred + (size_t)(b * 255 + a * 85) * HW + hw;
        const float* pc = pb + (size_t)5 * HW;
        int lab = t.label;

        // lane-parallel class logit loads (lane l -> class l; lanes 0..15 also l+64)
        float xc0 = pc[(size_t)lane * HW];
        float xc1 = (lane < 16) ? pc[(size_t)(lane + 64) * HW] : 0.f;
        clsp = bce0(xc0) - ((lane == lab) ? xc0 : 0.f);
        if (lane < 16) clsp += bce0(xc1) - ((lane + 64 == lab) ? xc1 : 0.f);

        // broadcast loads (same address across lanes)
        float px = pb[0], py = pb[(size_t)HW];
        float pw = pb[2 * (size_t)HW], ph = pb[3 * (size_t)HW];
        float xo = pb[4 * (size_t)HW];

        // objectness correction:  bal * (0.5*bce0(xo) - xo)
        objc = c_bal[s] * (0.5f * bce0(xo) - xo);

        // CIoU (computed redundantly on all lanes)
        const float stride = c_stride[s];
        const float aw = c_anch[s][a][0], ah = c_anch[s][a][1];
        float sx = 1.f / (1.f + __expf(-px));
        float sy = 1.f / (1.f + __expf(-py));
        float b1x = (sx + (float)gj) * stride, b1y = (sy + (float)gi) * stride;
        float b1w = __expf(pw) * aw,           b1h = __expf(ph) * ah;
        float b2x = ((float)gj + t.tx) * stride, b2y = ((float)gi + t.ty) * stride;
        float b2w = __expf(t.tw) * aw,           b2h = __expf(t.th) * ah;

        float b1x1 = b1x - b1w * 0.5f, b1x2 = b1x + b1w * 0.5f;
        float b1y1 = b1y - b1h * 0.5f, b1y2 = b1y + b1h * 0.5f;
        float b2x1 = b2x - b2w * 0.5f, b2x2 = b2x + b2w * 0.5f;
        float b2y1 = b2y - b2h * 0.5f, b2y2 = b2y + b2h * 0.5f;
        float iw = fmaxf(fminf(b1x2, b2x2) - fmaxf(b1x1, b2x1), 0.f);
        float ih = fmaxf(fminf(b1y2, b2y2) - fmaxf(b1y1, b2y1), 0.f);
        float inter = iw * ih;
        float uni = b1w * b1h + b2w * b2h - inter + EPSF;
        float iou = inter / uni;
        float cwv = fmaxf(b1x2, b2x2) - fminf(b1x1, b2x1);
        float chv = fmaxf(b1y2, b2y2) - fminf(b1y1, b2y1);
        float c2 = cwv * cwv + chv * chv + EPSF;
        float dx = b2x1 + b2x2 - b1x1 - b1x2;
        float dy = b2y1 + b2y2 - b1y1 - b1y2;
        float rho2 = (dx * dx + dy * dy) * 0.25f;
        float dat = atanf(b2w / (b2h + EPSF)) - atanf(b1w / (b1h + EPSF));
        float v = (4.f / (float)(M_PI * M_PI)) * dat * dat;
        float alpha = v / (v - iou + 1.f + EPSF);
        boxc = 1.f - (iou - (rho2 / c2 + v * alpha));
    }

    // cls: shfl reduce across the wave; box/obj are lane-redundant (take lane 0)
    for (int o = 32; o > 0; o >>= 1) clsp += __shfl_down(clsp, o);

    __shared__ float red[4][3];
    int wv = threadIdx.x >> 6;
    if (lane == 0) { red[wv][0] = boxc; red[wv][1] = objc; red[wv][2] = clsp; }
    __syncthreads();
    if (threadIdx.x == 0) {
        float bs = 0.f, os = 0.f, cs = 0.f;
        for (int i = 0; i < 4; ++i) { bs += red[i][0]; os += red[i][1]; cs += red[i][2]; }
        posPart[blockIdx.x * 4 + 0] = bs;   // box (scale = blockIdx.x/128)
        posPart[blockIdx.x * 4 + 1] = os;   // obj correction (bal folded)
        posPart[blockIdx.x * 4 + 2] = cs;   // cls (raw)
        posPart[blockIdx.x * 4 + 3] = 0.f;
    }
}

// ---------------------------------------------------------------------------
// Kernel 4: final reduce of partials -> scalar loss
// ---------------------------------------------------------------------------
__global__ __launch_bounds__(256) void finalize(
        const float* __restrict__ densePart, const float* __restrict__ posPart,
        const int* __restrict__ npos, float* __restrict__ out)
{
    int tid = threadIdx.x;
    float objd = 0.f;
    for (int i = tid; i < 394; i += 256) objd += densePart[i];
    float bx0 = 0.f, bx1 = 0.f, bx2 = 0.f, objc = 0.f, cls = 0.f;
    for (int blk = tid; blk < 384; blk += 256) {
        float bv = posPart[blk * 4 + 0];
        objc += posPart[blk * 4 + 1];
        cls  += posPart[blk * 4 + 2];
        int s = blk >> 7;
        bx0 += (s == 0) ? bv : 0.f;
        bx1 += (s == 1) ? bv : 0.f;
        bx2 += (s == 2) ? bv : 0.f;
    }
    for (int o = 32; o > 0; o >>= 1) {
        objd += __shfl_down(objd, o);
        bx0  += __shfl_down(bx0, o);
        bx1  += __shfl_down(bx1, o);
        bx2  += __shfl_down(bx2, o);
        objc += __shfl_down(objc, o);
        cls  += __shfl_down(cls, o);
    }
    __shared__ float red[4][6];
    int wv = tid >> 6;
    if ((tid & 63) == 0) {
        red[wv][0] = objd; red[wv][1] = bx0; red[wv][2] = bx1;
        red[wv][3] = bx2;  red[wv][4] = objc; red[wv][5] = cls;
    }
    __syncthreads();
    if (tid == 0) {
        float v[6] = {0, 0, 0, 0, 0, 0};
        for (int i = 0; i < 4; ++i)
            for (int j = 0; j < 6; ++j) v[j] += red[i][j];
        float tot = v[1] / fmaxf((float)npos[0], 1.f)
                  + v[2] / fmaxf((float)npos[1], 1.f)
                  + v[3] / fmaxf((float)npos[2], 1.f)
                  + (v[0] + v[4])      // dense obj + positive corrections
                  + 0.5f * v[5];       // LAMBDA_CLS
        out[0] = tot / 16.f;           // / B
    }
}

extern "C" void kernel_launch(void* const* d_in, const int* in_sizes, int n_in,
                              void* d_out, int out_size, void* d_ws, size_t ws_size,
                              hipStream_t stream)
{
    const float* p0     = (const float*)d_in[0];
    const float* p1     = (const float*)d_in[1];
    const float* p2     = (const float*)d_in[2];
    const float* boxes  = (const float*)d_in[3];
    const int*   labels = (const int*)d_in[4];

    char* ws = (char*)d_ws;
    Tgt*          tgt       = (Tgt*)ws;                       // 1536*32  = 49152 B
    unsigned int* winmask   = (unsigned int*)(ws + 49152);    // 48*4     = 192 B
    int*          npos      = (int*)(ws + 49408);             // 3*4
    float*        densePart = (float*)(ws + 49536);           // 394*4    = 1576 B
    float*        posPart   = (float*)(ws + 51200);           // 384*16   = 6144 B

    build_targets<<<1, 64, 0, stream>>>(boxes, labels, tgt, winmask, npos);
    dense_obj<<<394, 256, 0, stream>>>(p0, p1, p2, densePart);
    pos_loss<<<384, 256, 0, stream>>>(p0, p1, p2, tgt, winmask, posPart);
    finalize<<<1, 256, 0, stream>>>(densePart, posPart, npos, (float*)d_out);
}

// Round 3
// 14.537 us; speedup vs baseline: 11.9115x; 3.8836x over previous
//
#include <hip/hip_runtime.h>
#include <math.h>

#define EPSF 1e-7f

__constant__ float c_anch[3][3][2] = {
    {{80.f,104.f},{128.f,240.f},{264.f,184.f}},
    {{480.f,976.f},{992.f,720.f},{944.f,1904.f}},
    {{3712.f,2880.f},{4992.f,6336.f},{11936.f,10432.f}}
};
__constant__ float c_stride[3] = {8.f, 16.f, 32.f};
__constant__ float c_bal[3]    = {4.f, 1.f, 0.4f};
__constant__ int   c_HW[3]     = {6400, 1600, 400};
__constant__ int   c_W[3]      = {80, 40, 20};

__device__ __forceinline__ float bce0(float x) {
    // BCE with target 0: max(x,0) + log(1+exp(-|x|))
    return fmaxf(x, 0.f) + __logf(1.f + __expf(-fabsf(x)));
}

// ---------------------------------------------------------------------------
// Fused kernel:
//   blocks [0,394)   : dense objectness reduce (float4 streaming)
//   blocks [394,778) : positive targets — per-block in-LDS target build +
//                      one wave per target (lane-parallel class BCE)
// ---------------------------------------------------------------------------
__global__ __launch_bounds__(256) void fused_main(
        const float* __restrict__ p0, const float* __restrict__ p1,
        const float* __restrict__ p2,
        const float* __restrict__ boxes, const int* __restrict__ labels,
        float* __restrict__ densePart, float* __restrict__ posPart,
        float* __restrict__ nposPart)
{
    __shared__ float redD[4];
    __shared__ int   skey[32], slab[32];
    __shared__ float stx[32], sty[32], stw[32], sth[32];

    int bid = blockIdx.x;
    int tid = threadIdx.x;
    int lane = tid & 63, wv = tid >> 6;

    if (bid < 394) {
        // ---------------- dense objectness path ----------------
        int v = bid * 256 + tid;
        float sum = 0.f;
        if (v < 100800) {
            int s, run, off, HW;
            const float* pred;
            if (v < 76800)      { s = 0; HW = 6400; run = v / 1600;          off = v - run * 1600;         pred = p0; }
            else if (v < 96000) { s = 1; HW = 1600; int u = v - 76800; run = u / 400; off = u - run * 400; pred = p1; }
            else                { s = 2; HW = 400;  int u = v - 96000; run = u / 100; off = u - run * 100; pred = p2; }
            int b = run / 3, a = run - b * 3;
            const float4* ptr = (const float4*)(pred + (size_t)(b * 255 + a * 85 + 4) * HW) + off;
            float4 x = *ptr;
            float w = 0.5f * c_bal[s];
            sum = w * (bce0(x.x) + bce0(x.y) + bce0(x.z) + bce0(x.w));
        }
        for (int o = 32; o > 0; o >>= 1) sum += __shfl_down(sum, o);
        if (lane == 0) redD[wv] = sum;
        __syncthreads();
        if (tid == 0)
            densePart[bid] = redD[0] + redD[1] + redD[2] + redD[3];
        return;
    }

    // ---------------- positive path ----------------
    int pb  = bid - 394;          // 0..383
    int s   = pb >> 7;            // 128 blocks per scale
    int b   = (pb >> 3) & 15;
    int grp = pb & 7;             // 4 targets per block: n = grp*4 + wave

    // Phase 1: lanes 0..31 (wave 0 region of tid<32) build all 32 targets in LDS
    if (tid < 32) {
        int n = tid;
        float4 bx = ((const float4*)boxes)[b * 32 + n];
        float cx = (bx.x + bx.z) * 0.5f, cy = (bx.y + bx.w) * 0.5f;
        float w  = bx.z - bx.x,          h  = bx.w - bx.y;
        float stride = c_stride[s];
        float xg = cx / stride, yg = cy / stride;
        int W = c_W[s];
        int gi = min(max((int)yg, 0), W - 1);   // row from y
        int gj = min(max((int)xg, 0), W - 1);   // col from x
        int best = 0; float bm = 1e30f;
        for (int k = 0; k < 3; ++k) {
            float aw = c_anch[s][k][0], ah = c_anch[s][k][1];
            float r0 = w / aw, r1 = h / ah;
            float m = fmaxf(r0, 1.f / r0) * fmaxf(r1, 1.f / r1);
            if (m < bm) { bm = m; best = k; }
        }
        float aw = c_anch[s][best][0], ah = c_anch[s][best][1];
        skey[n] = (best << 20) | (gi << 10) | gj;
        stx[n]  = xg - (float)gj;
        sty[n]  = yg - (float)gi;
        stw[n]  = __logf(w / (aw + 1e-16f));
        sth[n]  = __logf(h / (ah + 1e-16f));
        slab[n] = labels[b * 32 + n];
    }
    __syncthreads();

    // npos contribution: one designated block per (s,b)
    if (grp == 0 && wv == 0) {
        bool win = false;
        if (lane < 32) {
            int k2 = skey[lane];
            win = true;
            for (int m = lane + 1; m < 32; ++m)
                if (skey[m] == k2) win = false;
        }
        unsigned long long bal = __ballot(win);
        if (lane == 0) nposPart[s * 16 + b] = (float)__popcll(bal);
    }

    // Phase 2: wave wv handles target n
    int n = grp * 4 + wv;
    int key = skey[n];
    bool win = true;
    for (int m = n + 1; m < 32; ++m)
        if (skey[m] == key) win = false;   // last-n-wins scatter semantics

    float boxc = 0.f, objc = 0.f, clsp = 0.f;
    if (win) {
        int a  = key >> 20;
        int gi = (key >> 10) & 1023;
        int gj = key & 1023;
        const int HW = c_HW[s], W = c_W[s];
        int hw = gi * W + gj;
        const float* pred = (s == 0) ? p0 : ((s == 1) ? p1 : p2);
        const float* pb_ = pred + (size_t)(b * 255 + a * 85) * HW + hw;
        const float* pc  = pb_ + (size_t)5 * HW;
        int lab = slab[n];

        // lane-parallel class logit loads (lane l -> class l; lanes 0..15 also l+64)
        float xc0 = pc[(size_t)lane * HW];
        float xc1 = (lane < 16) ? pc[(size_t)(lane + 64) * HW] : 0.f;
        clsp = bce0(xc0) - ((lane == lab) ? xc0 : 0.f);
        if (lane < 16) clsp += bce0(xc1) - ((lane + 64 == lab) ? xc1 : 0.f);

        float px = pb_[0], py = pb_[(size_t)HW];
        float pw = pb_[2 * (size_t)HW], ph = pb_[3 * (size_t)HW];
        float xo = pb_[4 * (size_t)HW];

        // objectness correction:  bal * (0.5*bce0(xo) - xo)
        objc = c_bal[s] * (0.5f * bce0(xo) - xo);

        // CIoU (lane-redundant)
        const float stride = c_stride[s];
        const float aw = c_anch[s][a][0], ah = c_anch[s][a][1];
        float sx = 1.f / (1.f + __expf(-px));
        float sy = 1.f / (1.f + __expf(-py));
        float b1x = (sx + (float)gj) * stride, b1y = (sy + (float)gi) * stride;
        float b1w = __expf(pw) * aw,           b1h = __expf(ph) * ah;
        float b2x = ((float)gj + stx[n]) * stride, b2y = ((float)gi + sty[n]) * stride;
        float b2w = __expf(stw[n]) * aw,           b2h = __expf(sth[n]) * ah;

        float b1x1 = b1x - b1w * 0.5f, b1x2 = b1x + b1w * 0.5f;
        float b1y1 = b1y - b1h * 0.5f, b1y2 = b1y + b1h * 0.5f;
        float b2x1 = b2x - b2w * 0.5f, b2x2 = b2x + b2w * 0.5f;
        float b2y1 = b2y - b2h * 0.5f, b2y2 = b2y + b2h * 0.5f;
        float iw = fmaxf(fminf(b1x2, b2x2) - fmaxf(b1x1, b2x1), 0.f);
        float ih = fmaxf(fminf(b1y2, b2y2) - fmaxf(b1y1, b2y1), 0.f);
        float inter = iw * ih;
        float uni = b1w * b1h + b2w * b2h - inter + EPSF;
        float iou = inter / uni;
        float cwv = fmaxf(b1x2, b2x2) - fminf(b1x1, b2x1);
        float chv = fmaxf(b1y2, b2y2) - fminf(b1y1, b2y1);
        float c2 = cwv * cwv + chv * chv + EPSF;
        float dx = b2x1 + b2x2 - b1x1 - b1x2;
        float dy = b2y1 + b2y2 - b1y1 - b1y2;
        float rho2 = (dx * dx + dy * dy) * 0.25f;
        float dat = atanf(b2w / (b2h + EPSF)) - atanf(b1w / (b1h + EPSF));
        float v = (4.f / (float)(M_PI * M_PI)) * dat * dat;
        float alpha = v / (v - iou + 1.f + EPSF);
        boxc = 1.f - (iou - (rho2 / c2 + v * alpha));
    }

    for (int o = 32; o > 0; o >>= 1) clsp += __shfl_down(clsp, o);
    if (lane == 0) {
        float* dst = posPart + (size_t)(pb * 4 + wv) * 4;
        dst[0] = boxc;   // box
        dst[1] = objc;   // obj correction (balance folded in)
        dst[2] = clsp;   // cls (raw)
        dst[3] = 0.f;
    }
}

// ---------------------------------------------------------------------------
// Finalize: reduce all partials -> scalar loss
// ---------------------------------------------------------------------------
__global__ __launch_bounds__(256) void finalize(
        const float* __restrict__ densePart, const float* __restrict__ posPart,
        const float* __restrict__ nposPart, float* __restrict__ out)
{
    int tid = threadIdx.x;
    float objd = 0.f;
    for (int i = tid; i < 394; i += 256) objd += densePart[i];

    float bx0 = 0.f, bx1 = 0.f, bx2 = 0.f, objc = 0.f, cls = 0.f;
    for (int i = tid; i < 1536; i += 256) {
        const float* src = posPart + (size_t)i * 4;
        float bv = src[0];
        objc += src[1];
        cls  += src[2];
        int s = i >> 9;      // 512 waves per scale
        bx0 += (s == 0) ? bv : 0.f;
        bx1 += (s == 1) ? bv : 0.f;
        bx2 += (s == 2) ? bv : 0.f;
    }
    float np0 = 0.f, np1 = 0.f, np2 = 0.f;
    if (tid < 48) {
        float v = nposPart[tid];
        int s = tid / 16;
        np0 = (s == 0) ? v : 0.f;
        np1 = (s == 1) ? v : 0.f;
        np2 = (s == 2) ? v : 0.f;
    }

    for (int o = 32; o > 0; o >>= 1) {
        objd += __shfl_down(objd, o);
        bx0  += __shfl_down(bx0, o);
        bx1  += __shfl_down(bx1, o);
        bx2  += __shfl_down(bx2, o);
        objc += __shfl_down(objc, o);
        cls  += __shfl_down(cls, o);
        np0  += __shfl_down(np0, o);
        np1  += __shfl_down(np1, o);
        np2  += __shfl_down(np2, o);
    }
    __shared__ float red[4][9];
    int wv = tid >> 6;
    if ((tid & 63) == 0) {
        red[wv][0] = objd; red[wv][1] = bx0; red[wv][2] = bx1; red[wv][3] = bx2;
        red[wv][4] = objc; red[wv][5] = cls; red[wv][6] = np0; red[wv][7] = np1;
        red[wv][8] = np2;
    }
    __syncthreads();
    if (tid == 0) {
        float v[9];
        for (int j = 0; j < 9; ++j)
            v[j] = red[0][j] + red[1][j] + red[2][j] + red[3][j];
        float tot = v[1] / fmaxf(v[6], 1.f)
                  + v[2] / fmaxf(v[7], 1.f)
                  + v[3] / fmaxf(v[8], 1.f)
                  + (v[0] + v[4])      // dense obj + positive corrections
                  + 0.5f * v[5];       // LAMBDA_CLS
        out[0] = tot / 16.f;           // / B
    }
}

extern "C" void kernel_launch(void* const* d_in, const int* in_sizes, int n_in,
                              void* d_out, int out_size, void* d_ws, size_t ws_size,
                              hipStream_t stream)
{
    const float* p0     = (const float*)d_in[0];
    const float* p1     = (const float*)d_in[1];
    const float* p2     = (const float*)d_in[2];
    const float* boxes  = (const float*)d_in[3];
    const int*   labels = (const int*)d_in[4];

    char* ws = (char*)d_ws;
    float* densePart = (float*)ws;                 // 394*4   = 1576 B
    float* posPart   = (float*)(ws + 2048);        // 1536*16 = 24576 B
    float* nposPart  = (float*)(ws + 2048 + 24576);// 48*4    = 192 B

    fused_main<<<778, 256, 0, stream>>>(p0, p1, p2, boxes, labels,
                                        densePart, posPart, nposPart);
    finalize<<<1, 256, 0, stream>>>(densePart, posPart, nposPart, (float*)d_out);
}